// Round 10
// baseline (262.438 us; speedup 1.0000x reference)
//
#include <hip/hip_runtime.h>
#include <hip/hip_bf16.h>
#include <math.h>

#define N_EMBD 768
#define N_HEAD 12
#define BATCH  2
#define SEQ    2048
#define ROWS   (BATCH*SEQ)   // 4096
#define C3     (3*N_EMBD)    // 2304

typedef __bf16 bf16;
typedef __attribute__((ext_vector_type(8))) __bf16 bf16x8;
typedef __attribute__((ext_vector_type(4))) float f32x4;

// async global->LDS, 16B per lane. LDS dest must be wave-uniform base + 16*lane.
__device__ __forceinline__ void async16(const bf16* g, bf16* l) {
    __builtin_amdgcn_global_load_lds(
        (const __attribute__((address_space(1))) uint32_t*)g,
        (__attribute__((address_space(3))) uint32_t*)l, 16, 0, 0);
}

// packed bf16 convert: w.lo = bf16(a), w.hi = bf16(b)
__device__ __forceinline__ unsigned cvt_pk_bf16(float a, float b) {
    unsigned w;
    asm("v_cvt_pk_bf16_f32 %0, %1, %2" : "=v"(w) : "v"(a), "v"(b));
    return w;
}

// ---------------- merged transpose+cast for all 4 weights: in[K,N] -> out[N,K] ----------------
__global__ __launch_bounds__(256) void k_transpose_all(
    const float* __restrict__ w0, bf16* __restrict__ o0,   // attn K=768  N=2304 (1728 tiles)
    const float* __restrict__ w1, bf16* __restrict__ o1,   // proj K=768  N=768  (576)
    const float* __restrict__ w2, bf16* __restrict__ o2,   // fc   K=768  N=3072 (2304)
    const float* __restrict__ w3, bf16* __restrict__ o3)   // mlp  K=3072 N=768  (2304)
{
    __shared__ bf16 tile[32][33];
    int bid = blockIdx.x;
    const float* in; bf16* out; int K, N, local;
    if      (bid < 1728) { in = w0; out = o0; K = 768;  N = 2304; local = bid; }
    else if (bid < 2304) { in = w1; out = o1; K = 768;  N = 768;  local = bid - 1728; }
    else if (bid < 4608) { in = w2; out = o2; K = 768;  N = 3072; local = bid - 2304; }
    else                 { in = w3; out = o3; K = 3072; N = 768;  local = bid - 4608; }
    int nt = N / 32;
    int n0 = (local % nt) * 32, k0 = (local / nt) * 32;
    int tc = threadIdx.x & 31, tr = threadIdx.x >> 5;
    #pragma unroll
    for (int i = 0; i < 4; i++) {
        int r = tr + i * 8;
        tile[r][tc] = (bf16)in[(size_t)(k0 + r) * N + n0 + tc];
    }
    __syncthreads();
    #pragma unroll
    for (int i = 0; i < 4; i++) {
        int r = tr + i * 8;
        out[(size_t)(n0 + r) * K + k0 + tc] = tile[tc][r];
    }
}

// ---------------- V transpose: qkv[t][2C + h*64 + d] -> vt[(bh*64+d)*SEQ + P(t)] ----------------
// Keys within each 32-group written in PERMUTED order
//   P(t) = ((t&15)>>2)*8 + ((t>>4)<<2) + (t&3)
// so chunk c of 8 holds keys {4c..4c+3, 16+4c..16+4c+3}. A PV fragment (kt,quad) is then
// ONE contiguous 16B chunk -> flash reads V as conflict-free ds_read_b128 (v10 pattern)
// while keeping in-register P. Same 64B line per (row, 32-group) -> write stays line-coalesced.
__global__ __launch_bounds__(256) void k_vtrans(
    const bf16* __restrict__ qkv, bf16* __restrict__ vt)
{
    __shared__ bf16 tile[32][33];
    int tt = blockIdx.x;                 // t tile (SEQ/32)
    int bh = blockIdx.y;                 // 24
    int dt = blockIdx.z;                 // d tile (2)
    int b = bh / N_HEAD, h = bh % N_HEAD;
    int tc = threadIdx.x & 31, tr = threadIdx.x >> 5;
    #pragma unroll
    for (int i = 0; i < 4; i++) {
        int r = tr + i * 8;              // t offset
        tile[r][tc] = qkv[(size_t)(b * SEQ + tt * 32 + r) * C3 + 2 * N_EMBD + h * 64 + dt * 32 + tc];
    }
    __syncthreads();
    int pos = ((tc & 15) >> 2) * 8 + ((tc >> 4) << 2) + (tc & 3);   // key permutation
    #pragma unroll
    for (int i = 0; i < 4; i++) {
        int r = tr + i * 8;              // d offset
        vt[(size_t)(bh * 64 + dt * 32 + r) * SEQ + tt * 32 + pos] = tile[tc][r];
    }
}

// ---------------- LayerNorm fp32 -> bf16, one wave per row, float4 loads ----------------
__global__ __launch_bounds__(256) void k_layernorm(
    const float* __restrict__ x, const float* __restrict__ g,
    const float* __restrict__ b, bf16* __restrict__ out)
{
    int wave = threadIdx.x >> 6, lane = threadIdx.x & 63;
    int row = blockIdx.x * 4 + wave;
    const float4* xr = (const float4*)(x + (size_t)row * N_EMBD);
    const float4* g4 = (const float4*)g;
    const float4* b4 = (const float4*)b;
    float4 v[3];
    float s = 0.f, sq = 0.f;
    #pragma unroll
    for (int i = 0; i < 3; i++) {
        v[i] = xr[lane + 64 * i];
        s  += v[i].x + v[i].y + v[i].z + v[i].w;
        sq += v[i].x * v[i].x + v[i].y * v[i].y + v[i].z * v[i].z + v[i].w * v[i].w;
    }
    #pragma unroll
    for (int off = 32; off > 0; off >>= 1) {
        s  += __shfl_xor(s, off);
        sq += __shfl_xor(sq, off);
    }
    float mu  = s * (1.f / N_EMBD);
    float var = sq * (1.f / N_EMBD) - mu * mu;
    float rs  = rsqrtf(var + 1e-5f);
    bf16* orow = out + (size_t)row * N_EMBD;
    #pragma unroll
    for (int i = 0; i < 3; i++) {
        float4 gv = g4[lane + 64 * i], bv = b4[lane + 64 * i];
        union { ushort4 u4; bf16 e[4]; } pk;
        pk.e[0] = (bf16)((v[i].x - mu) * rs * gv.x + bv.x);
        pk.e[1] = (bf16)((v[i].y - mu) * rs * gv.y + bv.y);
        pk.e[2] = (bf16)((v[i].z - mu) * rs * gv.z + bv.z);
        pk.e[3] = (bf16)((v[i].w - mu) * rs * gv.w + bv.w);
        *(ushort4*)&orow[(lane + 64 * i) * 4] = pk.u4;
    }
}

// ---------------- GEMM (4-wave, 128xBN, BK templated): r6 core + BK=32 dbuf path ----------------
// r10: qkv/fc instantiated at BN=64 -> grid supply 4.5/6 blocks/CU (was 2.25/3),
// LDS 24KB -> 6 blocks/CU capacity. Cross-block overlap replaces within-block ILP
// (r5/r6 counters: MfmaUtil 16%, Occ 14% = supply-limited).
template<int BN, int BK, int ACT, bool RES, bool OUT_BF16, bool MSWAP, bool DBUF>
__global__ __launch_bounds__(256) void k_gemm(
    const bf16* __restrict__ A, const bf16* __restrict__ Bt,
    const float* __restrict__ bias, const float* __restrict__ res,
    void* __restrict__ outp, int M, int N, int K)
{
    constexpr int WC  = BN / 64;
    constexpr int WR  = 4 / WC;
    constexpr int RPW = 128 / WR;
    constexpr int MI  = RPW / 16;
    constexpr int NB  = DBUF ? 2 : 1;
    constexpr int KH  = BK / 32;          // 16x16x32 passes per K-step
    constexpr int CPR = BK / 8;           // 16B chunks per row
    constexpr int RSTEP = 256 / CPR;      // rows staged per pass
    __shared__ __align__(16) bf16 As[NB][128 * BK];
    __shared__ __align__(16) bf16 Bs[NB][BN * BK];
    int n0 = (MSWAP ? blockIdx.y : blockIdx.x) * BN;
    int m0 = (MSWAP ? blockIdx.x : blockIdx.y) * 128;
    int t = threadIdx.x;
    int lane = t & 63, wave = t >> 6;
    int wr = wave / WC, wc = wave % WC;
    int quad = lane >> 4, l16 = lane & 15;

    f32x4 acc[MI][4];
    #pragma unroll
    for (int i = 0; i < MI; i++)
        #pragma unroll
        for (int j = 0; j < 4; j++) acc[i][j] = (f32x4){0.f, 0.f, 0.f, 0.f};

    int sr = t / CPR;           // staging row
    int sc = t % CPR;           // staging chunk
    int fsw = (BK == 64) ? (sr & 7) : ((sr & 3) ^ ((sr >> 2) & 3));
    int gsw = (sc ^ fsw) * 8;   // swizzled global column offset
    int lsw = (BK == 64) ? (l16 & 7) : ((l16 & 3) ^ ((l16 >> 2) & 3));

    auto stage = [&](int k0, int bi) {
        #pragma unroll
        for (int p = 0; p < 128 / RSTEP; p++) {
            int r = sr + p * RSTEP;
            async16(&A[(size_t)(m0 + r) * K + k0 + gsw], &As[bi][r * BK + sc * 8]);
        }
        #pragma unroll
        for (int p = 0; p < BN / RSTEP; p++) {
            int r = sr + p * RSTEP;
            async16(&Bt[(size_t)(n0 + r) * K + k0 + gsw], &Bs[bi][r * BK + sc * 8]);
        }
    };
    auto compute = [&](int bi) {
        #pragma unroll
        for (int kh = 0; kh < KH; kh++) {
            int qk = quad + 4 * kh;
            bf16x8 af[MI], bfv[4];
            #pragma unroll
            for (int i = 0; i < MI; i++)
                af[i]  = *(bf16x8*)&As[bi][(wr * RPW + i * 16 + l16) * BK + ((qk ^ lsw) * 8)];
            #pragma unroll
            for (int j = 0; j < 4; j++)
                bfv[j] = *(bf16x8*)&Bs[bi][(wc * 64 + j * 16 + l16) * BK + ((qk ^ lsw) * 8)];
            #pragma unroll
            for (int i = 0; i < MI; i++)
                #pragma unroll
                for (int j = 0; j < 4; j++)
                    acc[i][j] = __builtin_amdgcn_mfma_f32_16x16x32_bf16(af[i], bfv[j], acc[i][j], 0, 0, 0);
        }
    };

    if (DBUF) {
        stage(0, 0);
        int bi = 0;
        for (int k0 = 0; k0 < K; k0 += BK, bi ^= 1) {
            __syncthreads();
            if (k0 + BK < K) stage(k0 + BK, bi ^ 1);
            compute(bi);
        }
    } else {
        for (int k0 = 0; k0 < K; k0 += BK) {
            __syncthreads();
            stage(k0, 0);
            __syncthreads();
            compute(0);
        }
    }

    float* outf = (float*)outp;
    bf16*  outb = (bf16*)outp;
    #pragma unroll
    for (int i = 0; i < MI; i++) {
        #pragma unroll
        for (int j = 0; j < 4; j++) {
            int col = n0 + wc * 64 + j * 16 + l16;
            float bv = bias[col];
            #pragma unroll
            for (int r = 0; r < 4; r++) {
                int row = m0 + wr * RPW + i * 16 + quad * 4 + r;
                float v = acc[i][j][r] + bv;
                if (ACT == 1) {
                    float z = 0.7978845608f * (v + 0.044715f * v * v * v);
                    v = v / (1.f + __expf(-2.f * z));   // 0.5v(1+tanh z) == v*sigmoid(2z)
                }
                if (RES) v += res[(size_t)row * N + col];
                if (OUT_BF16) outb[(size_t)row * N + col] = (bf16)v;
                else          outf[(size_t)row * N + col] = v;
            }
        }
    }
}

// ---------------- GEMM2 (4-wave, 64x64 tile, dbuf): for N=768 GEMMs ----------------
__global__ __launch_bounds__(256) void k_gemm2(
    const bf16* __restrict__ A, const bf16* __restrict__ Bt,
    const float* __restrict__ bias, const float* __restrict__ res,
    float* __restrict__ outp, int M, int N, int K)
{
    __shared__ __align__(16) bf16 As[2][64 * 64];
    __shared__ __align__(16) bf16 Bs[2][64 * 64];
    int m0 = blockIdx.x * 64, n0 = blockIdx.y * 64;
    int t = threadIdx.x;
    int lane = t & 63, w = t >> 6;       // w 0..3
    int wr = w >> 1, wcol = w & 1;       // 2x2 wave grid
    int quad = lane >> 4, l16 = lane & 15;

    f32x4 acc[2][2];
    #pragma unroll
    for (int i = 0; i < 2; i++)
        #pragma unroll
        for (int j = 0; j < 2; j++) acc[i][j] = (f32x4){0.f, 0.f, 0.f, 0.f};

    int sr = t >> 3;            // 0..31 (row)
    int sc = t & 7;             // chunk 0..7
    int gsw = (sc ^ (sr & 7)) * 8;   // (sr+32)&7 == sr&7

    auto stage = [&](int k0, int bi) {
        #pragma unroll
        for (int p = 0; p < 2; p++) {
            int r = sr + p * 32;
            async16(&A[(size_t)(m0 + r) * K + k0 + gsw], &As[bi][r * 64 + sc * 8]);
            async16(&Bt[(size_t)(n0 + r) * K + k0 + gsw], &Bs[bi][r * 64 + sc * 8]);
        }
    };
    auto compute = [&](int bi) {
        #pragma unroll
        for (int kh = 0; kh < 2; kh++) {
            int rsw = ((quad + 4 * kh) ^ (l16 & 7)) * 8;
            bf16x8 af[2], bfv[2];
            #pragma unroll
            for (int i = 0; i < 2; i++)
                af[i]  = *(bf16x8*)&As[bi][(wr * 32 + i * 16 + l16) * 64 + rsw];
            #pragma unroll
            for (int j = 0; j < 2; j++)
                bfv[j] = *(bf16x8*)&Bs[bi][(wcol * 32 + j * 16 + l16) * 64 + rsw];
            #pragma unroll
            for (int i = 0; i < 2; i++)
                #pragma unroll
                for (int j = 0; j < 2; j++)
                    acc[i][j] = __builtin_amdgcn_mfma_f32_16x16x32_bf16(af[i], bfv[j], acc[i][j], 0, 0, 0);
        }
    };

    stage(0, 0);
    int bi = 0;
    for (int k0 = 0; k0 < K; k0 += 64, bi ^= 1) {
        __syncthreads();
        if (k0 + 64 < K) stage(k0 + 64, bi ^ 1);
        compute(bi);
    }

    #pragma unroll
    for (int i = 0; i < 2; i++) {
        #pragma unroll
        for (int j = 0; j < 2; j++) {
            int col = n0 + wcol * 32 + j * 16 + l16;
            float bv = bias[col];
            #pragma unroll
            for (int r = 0; r < 4; r++) {
                int row = m0 + wr * 32 + i * 16 + quad * 4 + r;
                outp[(size_t)row * N + col] = acc[i][j][r] + bv + res[(size_t)row * N + col];
            }
        }
    }
}

// ---------------- Flash attention v14 (r9-validated): in-register P + pre-permuted V ----------------
// 41.4us, 0 bank conflicts. Swapped QK^T (S^T = mfma(K,Q)), cvt_pk pa pack, no Ps
// buffer (LDS 32768), scalar l_part, exp2 softmax, b128 PV via permuted vt.
__global__ __launch_bounds__(256) void k_flash(
    const bf16* __restrict__ qkv, const bf16* __restrict__ vt, bf16* __restrict__ y)
{
    __shared__ __align__(16) bf16 Ks[2][64 * 64];      // [buf][key][d ^ swz]
    __shared__ __align__(16) bf16 VTl[2][64 * 64];     // [buf][d][permuted-key ^ swz]
    int bid = blockIdx.x;
    int hi = bid >> 8;                   // 0..2
    int lo = bid & 255;
    int g  = lo >> 3;                    // 0..31
    int e  = lo & 7;                     // 0..7
    int bh = hi * 8 + e;                 // 0..23
    int qt;
    if      (hi == 0) qt = g;
    else if (hi == 1) qt = (g + 16) & 31;
    else              qt = (g < 16) ? (30 - 2 * g) : (63 - 2 * g);
    int b = bh / N_HEAD, h = bh % N_HEAD;
    int t = threadIdx.x, lane = t & 63, wave = t >> 6;
    int quad = lane >> 4, l16 = lane & 15;
    int qbase = qt * 64 + wave * 16;
    int qself = qbase + l16;             // this lane's q row (after swap)

    // Q fragments, pre-scaled by log2(e)/8 (softmax uses exp2)
    bf16x8 qa[2];
    {
        const float qsc = 0.125f * 1.44269504089f;
        const bf16* qrow = qkv + (size_t)(b * SEQ + qbase + l16) * C3 + h * 64;
        #pragma unroll
        for (int kh = 0; kh < 2; kh++) {
            union { uint4 u4; bf16 e8[8]; bf16x8 vv; } uq;
            uq.u4 = *(const uint4*)&qrow[quad * 8 + kh * 32];
            #pragma unroll
            for (int j = 0; j < 8; j++) uq.e8[j] = (bf16)((float)uq.e8[j] * qsc);
            qa[kh] = uq.vv;
        }
    }
    float l_part = 0.f;                  // scalar: sum over this lane's keys for q=l16
    f32x4 o[4];
    #pragma unroll
    for (int j = 0; j < 4; j++) o[j] = (f32x4){0.f, 0.f, 0.f, 0.f};

    int sr = t >> 3;                 // 0..31 (staging row)
    int sc = t & 7;                  // 16B chunk
    int gsw = (sc ^ (sr & 7)) * 8;   // swizzled column offset (shared by K and V)

    const bf16* kg = qkv + (size_t)b * SEQ * C3 + N_EMBD + h * 64;
    const bf16* vg = vt + (size_t)bh * 64 * SEQ;

    auto stage = [&](int tile, int bufi) {
        int k0 = tile * 64;
        #pragma unroll
        for (int p = 0; p < 2; p++) {
            int rr = sr + 32 * p;
            async16(&kg[(size_t)(k0 + rr) * C3 + gsw], &Ks[bufi][rr * 64 + sc * 8]);
            async16(&vg[(size_t)rr * SEQ + k0 + gsw], &VTl[bufi][rr * 64 + sc * 8]);
        }
    };

    int ntiles = qt + 1;
    stage(0, 0);

    for (int tt = 0; tt < ntiles; tt++) {
        int bufi = tt & 1;
        int k0 = tt * 64;
        __syncthreads();                       // drains buf's loads (issued a full tile ago)
        if (tt + 1 < ntiles) stage(tt + 1, bufi ^ 1);

        // S^T = K Q^T (swapped operands; K read identical to v10)
        // s[nt]: lane holds S[key = k0+nt*16+quad*4+r][q = qbase+l16]
        f32x4 s[4];
        __builtin_amdgcn_s_setprio(1);
        #pragma unroll
        for (int nt = 0; nt < 4; nt++) {
            bf16x8 b0 = *(bf16x8*)&Ks[bufi][(nt * 16 + l16) * 64 + (((quad    ) ^ (l16 & 7)) * 8)];
            bf16x8 b1 = *(bf16x8*)&Ks[bufi][(nt * 16 + l16) * 64 + (((quad + 4) ^ (l16 & 7)) * 8)];
            f32x4 z = (f32x4){0.f, 0.f, 0.f, 0.f};
            z = __builtin_amdgcn_mfma_f32_16x16x32_bf16(b0, qa[0], z, 0, 0, 0);
            z = __builtin_amdgcn_mfma_f32_16x16x32_bf16(b1, qa[1], z, 0, 0, 0);
            s[nt] = z;
        }
        __builtin_amdgcn_s_setprio(0);

        // p = exp2(s); causal zeroing only on the diagonal tile; l_part scalar
        bool diag = (tt == qt);
        float p[4][4];
        #pragma unroll
        for (int nt = 0; nt < 4; nt++) {
            int keyb = k0 + nt * 16 + quad * 4;
            #pragma unroll
            for (int r = 0; r < 4; r++) {
                float pv = exp2f(s[nt][r]);
                if (diag && keyb + r > qself) pv = 0.f;
                p[nt][r] = pv;
                l_part += pv;
            }
        }

        // pa: packed-placement build via v_cvt_pk_bf16_f32 (8 ops)
        // pa[kt].e8 = { P[kt*32+quad*4+0..3], P[kt*32+16+quad*4+0..3] } (permuted k-axis)
        bf16x8 pa[2];
        #pragma unroll
        for (int kt = 0; kt < 2; kt++) {
            union { unsigned u[4]; bf16x8 vv; } pk;
            pk.u[0] = cvt_pk_bf16(p[2 * kt][0],     p[2 * kt][1]);
            pk.u[1] = cvt_pk_bf16(p[2 * kt][2],     p[2 * kt][3]);
            pk.u[2] = cvt_pk_bf16(p[2 * kt + 1][0], p[2 * kt + 1][1]);
            pk.u[3] = cvt_pk_bf16(p[2 * kt + 1][2], p[2 * kt + 1][3]);
            pa[kt] = pk.vv;
        }

        // O += P V : pre-permuted vt makes the fragment one b128 (v10's conflict-free pattern)
        __builtin_amdgcn_s_setprio(1);
        #pragma unroll
        for (int jt = 0; jt < 4; jt++) {
            int d = jt * 16 + l16;
            #pragma unroll
            for (int kt = 0; kt < 2; kt++) {
                bf16x8 vb = *(bf16x8*)&VTl[bufi][d * 64 + (((quad + 4 * kt) ^ (l16 & 7)) * 8)];
                o[jt] = __builtin_amdgcn_mfma_f32_16x16x32_bf16(pa[kt], vb, o[jt], 0, 0, 0);
            }
        }
        __builtin_amdgcn_s_setprio(0);
    }

    // epilogue: finish l over all keys (reduce across quads), redistribute to o's q rows
    l_part += __shfl_xor(l_part, 16);
    l_part += __shfl_xor(l_part, 32);    // now lane (l16, any quad) holds total for q=l16
    float inv[4];
    #pragma unroll
    for (int r = 0; r < 4; r++)
        inv[r] = 1.f / __shfl(l_part, quad * 4 + r);   // lane quad*4+r holds q=quad*4+r
    #pragma unroll
    for (int jt = 0; jt < 4; jt++)
        #pragma unroll
        for (int r = 0; r < 4; r++) {
            int q = qbase + quad * 4 + r;
            y[(size_t)(b * SEQ + q) * N_EMBD + h * 64 + jt * 16 + l16] =
                (bf16)(o[jt][r] * inv[r]);
        }
}

// ---------------- launcher ----------------
extern "C" void kernel_launch(void* const* d_in, const int* in_sizes, int n_in,
                              void* d_out, int out_size, void* d_ws, size_t ws_size,
                              hipStream_t stream) {
    const float* x           = (const float*)d_in[0];
    const float* ln1_g       = (const float*)d_in[1];
    const float* ln1_b       = (const float*)d_in[2];
    const float* w_attn      = (const float*)d_in[3];
    const float* b_attn      = (const float*)d_in[4];
    const float* w_attn_proj = (const float*)d_in[5];
    const float* b_attn_proj = (const float*)d_in[6];
    const float* ln2_g       = (const float*)d_in[7];
    const float* ln2_b       = (const float*)d_in[8];
    const float* w_fc        = (const float*)d_in[9];
    const float* b_fc        = (const float*)d_in[10];
    const float* w_mlp_proj  = (const float*)d_in[11];
    const float* b_mlp_proj  = (const float*)d_in[12];

    char* ws = (char*)d_ws;
    size_t off = 0;
    auto alloc = [&](size_t n) -> void* {
        off = (off + 255) & ~(size_t)255;
        void* p = ws + off;
        off += n;
        return p;
    };
    bf16* wqkvT  = (bf16*)alloc((size_t)C3 * N_EMBD * 2);
    bf16* wprojT = (bf16*)alloc((size_t)N_EMBD * N_EMBD * 2);
    bf16* wfcT   = (bf16*)alloc((size_t)4 * N_EMBD * N_EMBD * 2);
    bf16* wmlpT  = (bf16*)alloc((size_t)N_EMBD * 4 * N_EMBD * 2);
    bf16* hbuf   = (bf16*)alloc((size_t)ROWS * N_EMBD * 2);
    float* x2    = (float*)alloc((size_t)ROWS * N_EMBD * 4);
    bf16* yb     = (bf16*)alloc((size_t)ROWS * N_EMBD * 2);
    bf16* vtb    = (bf16*)alloc((size_t)BATCH * N_HEAD * 64 * SEQ * 2);
    bf16* big    = (bf16*)alloc((size_t)ROWS * 4 * N_EMBD * 2);
    bf16* qkvb   = big;        // [ROWS, 2304]
    bf16* actb   = big;        // [ROWS, 3072]

    k_transpose_all<<<6912, 256, 0, stream>>>(w_attn, wqkvT, w_attn_proj, wprojT,
                                              w_fc, wfcT, w_mlp_proj, wmlpT);

    k_layernorm<<<ROWS / 4, 256, 0, stream>>>(x, ln1_g, ln1_b, hbuf);
    // qkv: m-fast grid, BN=64 (1152 blocks = 4.5/CU), BK=32 dbuf
    k_gemm<64, 32, 0, false, true,  true,  true><<<dim3(ROWS / 128, C3 / 64), 256, 0, stream>>>(
        hbuf, wqkvT,  b_attn,      nullptr, qkvb, ROWS, C3,     N_EMBD);
    k_vtrans<<<dim3(SEQ / 32, BATCH * N_HEAD, 2), 256, 0, stream>>>(qkvb, vtb);
    k_flash<<<768, 256, 0, stream>>>(qkvb, vtb, yb);
    // proj: 64x64 4-wave blocks, 3 blocks/CU
    k_gemm2<<<dim3(ROWS / 64, N_EMBD / 64), 256, 0, stream>>>(
        yb,   wprojT, b_attn_proj, x,       x2,   ROWS, N_EMBD, N_EMBD);
    k_layernorm<<<ROWS / 4, 256, 0, stream>>>(x2, ln2_g, ln2_b, hbuf);
    // fc: m-fast grid, BN=64 (1536 blocks = 6/CU), BK=32 dbuf
    k_gemm<64, 32, 1, false, true,  true,  true><<<dim3(ROWS / 128, 3072 / 64), 256, 0, stream>>>(
        hbuf, wfcT,   b_fc,        nullptr, actb, ROWS, 3072,   N_EMBD);
    // mlp: 64x64 4-wave blocks, 3 blocks/CU
    k_gemm2<<<dim3(ROWS / 64, N_EMBD / 64), 256, 0, stream>>>(
        actb, wmlpT,  b_mlp_proj,  x2, (float*)d_out, ROWS, N_EMBD, 3072);
}

// Round 11
// 258.753 us; speedup vs baseline: 1.0142x; 1.0142x over previous
//
#include <hip/hip_runtime.h>
#include <hip/hip_bf16.h>
#include <math.h>

#define N_EMBD 768
#define N_HEAD 12
#define BATCH  2
#define SEQ    2048
#define ROWS   (BATCH*SEQ)   // 4096
#define C3     (3*N_EMBD)    // 2304

typedef __bf16 bf16;
typedef __attribute__((ext_vector_type(8))) __bf16 bf16x8;
typedef __attribute__((ext_vector_type(4))) float f32x4;

// async global->LDS, 16B per lane. LDS dest must be wave-uniform base + 16*lane.
__device__ __forceinline__ void async16(const bf16* g, bf16* l) {
    __builtin_amdgcn_global_load_lds(
        (const __attribute__((address_space(1))) uint32_t*)g,
        (__attribute__((address_space(3))) uint32_t*)l, 16, 0, 0);
}

// packed bf16 convert: w.lo = bf16(a), w.hi = bf16(b)
__device__ __forceinline__ unsigned cvt_pk_bf16(float a, float b) {
    unsigned w;
    asm("v_cvt_pk_bf16_f32 %0, %1, %2" : "=v"(w) : "v"(a), "v"(b));
    return w;
}

// ---------------- merged transpose+cast for all 4 weights: in[K,N] -> out[N,K] ----------------
__global__ __launch_bounds__(256) void k_transpose_all(
    const float* __restrict__ w0, bf16* __restrict__ o0,   // attn K=768  N=2304 (1728 tiles)
    const float* __restrict__ w1, bf16* __restrict__ o1,   // proj K=768  N=768  (576)
    const float* __restrict__ w2, bf16* __restrict__ o2,   // fc   K=768  N=3072 (2304)
    const float* __restrict__ w3, bf16* __restrict__ o3)   // mlp  K=3072 N=768  (2304)
{
    __shared__ bf16 tile[32][33];
    int bid = blockIdx.x;
    const float* in; bf16* out; int K, N, local;
    if      (bid < 1728) { in = w0; out = o0; K = 768;  N = 2304; local = bid; }
    else if (bid < 2304) { in = w1; out = o1; K = 768;  N = 768;  local = bid - 1728; }
    else if (bid < 4608) { in = w2; out = o2; K = 768;  N = 3072; local = bid - 2304; }
    else                 { in = w3; out = o3; K = 3072; N = 768;  local = bid - 4608; }
    int nt = N / 32;
    int n0 = (local % nt) * 32, k0 = (local / nt) * 32;
    int tc = threadIdx.x & 31, tr = threadIdx.x >> 5;
    #pragma unroll
    for (int i = 0; i < 4; i++) {
        int r = tr + i * 8;
        tile[r][tc] = (bf16)in[(size_t)(k0 + r) * N + n0 + tc];
    }
    __syncthreads();
    #pragma unroll
    for (int i = 0; i < 4; i++) {
        int r = tr + i * 8;
        out[(size_t)(n0 + r) * K + k0 + tc] = tile[tc][r];
    }
}

// ---------------- V transpose: qkv[t][2C + h*64 + d] -> vt[(bh*64+d)*SEQ + P(t)] ----------------
// Keys within each 32-group written in PERMUTED order
//   P(t) = ((t&15)>>2)*8 + ((t>>4)<<2) + (t&3)
// so chunk c of 8 holds keys {4c..4c+3, 16+4c..16+4c+3}. A PV fragment (kt,quad) is then
// ONE contiguous 16B chunk -> flash reads V as conflict-free ds_read_b128 (v10 pattern)
// while keeping in-register P.
__global__ __launch_bounds__(256) void k_vtrans(
    const bf16* __restrict__ qkv, bf16* __restrict__ vt)
{
    __shared__ bf16 tile[32][33];
    int tt = blockIdx.x;                 // t tile (SEQ/32)
    int bh = blockIdx.y;                 // 24
    int dt = blockIdx.z;                 // d tile (2)
    int b = bh / N_HEAD, h = bh % N_HEAD;
    int tc = threadIdx.x & 31, tr = threadIdx.x >> 5;
    #pragma unroll
    for (int i = 0; i < 4; i++) {
        int r = tr + i * 8;              // t offset
        tile[r][tc] = qkv[(size_t)(b * SEQ + tt * 32 + r) * C3 + 2 * N_EMBD + h * 64 + dt * 32 + tc];
    }
    __syncthreads();
    int pos = ((tc & 15) >> 2) * 8 + ((tc >> 4) << 2) + (tc & 3);   // key permutation
    #pragma unroll
    for (int i = 0; i < 4; i++) {
        int r = tr + i * 8;              // d offset
        vt[(size_t)(bh * 64 + dt * 32 + r) * SEQ + tt * 32 + pos] = tile[tc][r];
    }
}

// ---------------- LayerNorm fp32 -> bf16, one wave per row, float4 loads ----------------
__global__ __launch_bounds__(256) void k_layernorm(
    const float* __restrict__ x, const float* __restrict__ g,
    const float* __restrict__ b, bf16* __restrict__ out)
{
    int wave = threadIdx.x >> 6, lane = threadIdx.x & 63;
    int row = blockIdx.x * 4 + wave;
    const float4* xr = (const float4*)(x + (size_t)row * N_EMBD);
    const float4* g4 = (const float4*)g;
    const float4* b4 = (const float4*)b;
    float4 v[3];
    float s = 0.f, sq = 0.f;
    #pragma unroll
    for (int i = 0; i < 3; i++) {
        v[i] = xr[lane + 64 * i];
        s  += v[i].x + v[i].y + v[i].z + v[i].w;
        sq += v[i].x * v[i].x + v[i].y * v[i].y + v[i].z * v[i].z + v[i].w * v[i].w;
    }
    #pragma unroll
    for (int off = 32; off > 0; off >>= 1) {
        s  += __shfl_xor(s, off);
        sq += __shfl_xor(sq, off);
    }
    float mu  = s * (1.f / N_EMBD);
    float var = sq * (1.f / N_EMBD) - mu * mu;
    float rs  = rsqrtf(var + 1e-5f);
    bf16* orow = out + (size_t)row * N_EMBD;
    #pragma unroll
    for (int i = 0; i < 3; i++) {
        float4 gv = g4[lane + 64 * i], bv = b4[lane + 64 * i];
        union { ushort4 u4; bf16 e[4]; } pk;
        pk.e[0] = (bf16)((v[i].x - mu) * rs * gv.x + bv.x);
        pk.e[1] = (bf16)((v[i].y - mu) * rs * gv.y + bv.y);
        pk.e[2] = (bf16)((v[i].z - mu) * rs * gv.z + bv.z);
        pk.e[3] = (bf16)((v[i].w - mu) * rs * gv.w + bv.w);
        *(ushort4*)&orow[(lane + 64 * i) * 4] = pk.u4;
    }
}

// ---------------- GEMM (4-wave, 128xBN, BK templated) ----------------
// PIPE=0: single-buffer 2-barrier. PIPE=1: dbuf 1-barrier (drain-all). PIPE=2 (r11):
// 3-buffer counted-vmcnt pipeline (T4-lite). r10 post-mortem: __syncthreads drains
// vmcnt(0) so the prefetch gets only ~80cy of cover vs ~300-600cy load latency --
// occupancy knobs can't fix a structural drain (occ 14->29% moved dur 0%). PIPE=2:
// s_waitcnt vmcnt(4) waits ONLY stage(k); stage(k+1) stays in flight across the raw
// s_barrier; stage(k+2) issued after. Loads get 2 full iterations to land.
// Safety: barrier-after-waitcnt publishes all waves' parts; buffer (k+2)%3 is only
// rewritten after the barrier that proves compute(k-1) done; tail peels to vmcnt(0).
template<int BN, int BK, int ACT, bool RES, bool OUT_BF16, bool MSWAP, int PIPE>
__global__ __launch_bounds__(256) void k_gemm(
    const bf16* __restrict__ A, const bf16* __restrict__ Bt,
    const float* __restrict__ bias, const float* __restrict__ res,
    void* __restrict__ outp, int M, int N, int K)
{
    constexpr int WC  = BN / 64;
    constexpr int WR  = 4 / WC;
    constexpr int RPW = 128 / WR;
    constexpr int MI  = RPW / 16;
    constexpr int NB  = (PIPE == 2) ? 3 : (PIPE == 1 ? 2 : 1);
    constexpr int KH  = BK / 32;          // 16x16x32 passes per K-step
    constexpr int CPR = BK / 8;           // 16B chunks per row
    constexpr int RSTEP = 256 / CPR;      // rows staged per pass
    __shared__ __align__(16) bf16 As[NB][128 * BK];
    __shared__ __align__(16) bf16 Bs[NB][BN * BK];
    int n0 = (MSWAP ? blockIdx.y : blockIdx.x) * BN;
    int m0 = (MSWAP ? blockIdx.x : blockIdx.y) * 128;
    int t = threadIdx.x;
    int lane = t & 63, wave = t >> 6;
    int wr = wave / WC, wc = wave % WC;
    int quad = lane >> 4, l16 = lane & 15;

    f32x4 acc[MI][4];
    #pragma unroll
    for (int i = 0; i < MI; i++)
        #pragma unroll
        for (int j = 0; j < 4; j++) acc[i][j] = (f32x4){0.f, 0.f, 0.f, 0.f};

    int sr = t / CPR;           // staging row
    int sc = t % CPR;           // staging chunk
    int fsw = (BK == 64) ? (sr & 7) : ((sr & 3) ^ ((sr >> 2) & 3));
    int gsw = (sc ^ fsw) * 8;   // swizzled global column offset
    int lsw = (BK == 64) ? (l16 & 7) : ((l16 & 3) ^ ((l16 >> 2) & 3));

    auto stage = [&](int k0, int bi) {
        #pragma unroll
        for (int p = 0; p < 128 / RSTEP; p++) {
            int r = sr + p * RSTEP;
            async16(&A[(size_t)(m0 + r) * K + k0 + gsw], &As[bi][r * BK + sc * 8]);
        }
        #pragma unroll
        for (int p = 0; p < BN / RSTEP; p++) {
            int r = sr + p * RSTEP;
            async16(&Bt[(size_t)(n0 + r) * K + k0 + gsw], &Bs[bi][r * BK + sc * 8]);
        }
    };
    auto compute = [&](int bi) {
        #pragma unroll
        for (int kh = 0; kh < KH; kh++) {
            int qk = quad + 4 * kh;
            bf16x8 af[MI], bfv[4];
            #pragma unroll
            for (int i = 0; i < MI; i++)
                af[i]  = *(bf16x8*)&As[bi][(wr * RPW + i * 16 + l16) * BK + ((qk ^ lsw) * 8)];
            #pragma unroll
            for (int j = 0; j < 4; j++)
                bfv[j] = *(bf16x8*)&Bs[bi][(wc * 64 + j * 16 + l16) * BK + ((qk ^ lsw) * 8)];
            #pragma unroll
            for (int i = 0; i < MI; i++)
                #pragma unroll
                for (int j = 0; j < 4; j++)
                    acc[i][j] = __builtin_amdgcn_mfma_f32_16x16x32_bf16(af[i], bfv[j], acc[i][j], 0, 0, 0);
        }
    };

    if (PIPE == 2) {
        static_assert(PIPE != 2 || (128 + BN) / RSTEP == 4, "vmcnt(4) assumes 4 loads/stage");
        stage(0, 0);
        stage(BK, 1);
        int bi = 0;
        for (int k0 = 0; k0 < K; k0 += BK) {
            if (k0 + BK < K) asm volatile("s_waitcnt vmcnt(4)" ::: "memory");
            else             asm volatile("s_waitcnt vmcnt(0)" ::: "memory");
            __builtin_amdgcn_s_barrier();
            __builtin_amdgcn_sched_barrier(0);
            if (k0 + 2 * BK < K) {
                int b2 = bi + 2; if (b2 >= 3) b2 -= 3;
                stage(k0 + 2 * BK, b2);
            }
            compute(bi);
            bi = (bi == 2) ? 0 : bi + 1;
        }
    } else if (PIPE == 1) {
        stage(0, 0);
        int bi = 0;
        for (int k0 = 0; k0 < K; k0 += BK, bi ^= 1) {
            __syncthreads();
            if (k0 + BK < K) stage(k0 + BK, bi ^ 1);
            compute(bi);
        }
    } else {
        for (int k0 = 0; k0 < K; k0 += BK) {
            __syncthreads();
            stage(k0, 0);
            __syncthreads();
            compute(0);
        }
    }

    float* outf = (float*)outp;
    bf16*  outb = (bf16*)outp;
    #pragma unroll
    for (int i = 0; i < MI; i++) {
        #pragma unroll
        for (int j = 0; j < 4; j++) {
            int col = n0 + wc * 64 + j * 16 + l16;
            float bv = bias[col];
            #pragma unroll
            for (int r = 0; r < 4; r++) {
                int row = m0 + wr * RPW + i * 16 + quad * 4 + r;
                float v = acc[i][j][r] + bv;
                if (ACT == 1) {
                    float z = 0.7978845608f * (v + 0.044715f * v * v * v);
                    v = v / (1.f + __expf(-2.f * z));   // 0.5v(1+tanh z) == v*sigmoid(2z)
                }
                if (RES) v += res[(size_t)row * N + col];
                if (OUT_BF16) outb[(size_t)row * N + col] = (bf16)v;
                else          outf[(size_t)row * N + col] = v;
            }
        }
    }
}

// ---------------- GEMM2 (4-wave, 64x64 tile, dbuf): for N=768 GEMMs ----------------
__global__ __launch_bounds__(256) void k_gemm2(
    const bf16* __restrict__ A, const bf16* __restrict__ Bt,
    const float* __restrict__ bias, const float* __restrict__ res,
    float* __restrict__ outp, int M, int N, int K)
{
    __shared__ __align__(16) bf16 As[2][64 * 64];
    __shared__ __align__(16) bf16 Bs[2][64 * 64];
    int m0 = blockIdx.x * 64, n0 = blockIdx.y * 64;
    int t = threadIdx.x;
    int lane = t & 63, w = t >> 6;       // w 0..3
    int wr = w >> 1, wcol = w & 1;       // 2x2 wave grid
    int quad = lane >> 4, l16 = lane & 15;

    f32x4 acc[2][2];
    #pragma unroll
    for (int i = 0; i < 2; i++)
        #pragma unroll
        for (int j = 0; j < 2; j++) acc[i][j] = (f32x4){0.f, 0.f, 0.f, 0.f};

    int sr = t >> 3;            // 0..31 (row)
    int sc = t & 7;             // chunk 0..7
    int gsw = (sc ^ (sr & 7)) * 8;   // (sr+32)&7 == sr&7

    auto stage = [&](int k0, int bi) {
        #pragma unroll
        for (int p = 0; p < 2; p++) {
            int r = sr + p * 32;
            async16(&A[(size_t)(m0 + r) * K + k0 + gsw], &As[bi][r * 64 + sc * 8]);
            async16(&Bt[(size_t)(n0 + r) * K + k0 + gsw], &Bs[bi][r * 64 + sc * 8]);
        }
    };
    auto compute = [&](int bi) {
        #pragma unroll
        for (int kh = 0; kh < 2; kh++) {
            int rsw = ((quad + 4 * kh) ^ (l16 & 7)) * 8;
            bf16x8 af[2], bfv[2];
            #pragma unroll
            for (int i = 0; i < 2; i++)
                af[i]  = *(bf16x8*)&As[bi][(wr * 32 + i * 16 + l16) * 64 + rsw];
            #pragma unroll
            for (int j = 0; j < 2; j++)
                bfv[j] = *(bf16x8*)&Bs[bi][(wcol * 32 + j * 16 + l16) * 64 + rsw];
            #pragma unroll
            for (int i = 0; i < 2; i++)
                #pragma unroll
                for (int j = 0; j < 2; j++)
                    acc[i][j] = __builtin_amdgcn_mfma_f32_16x16x32_bf16(af[i], bfv[j], acc[i][j], 0, 0, 0);
        }
    };

    stage(0, 0);
    int bi = 0;
    for (int k0 = 0; k0 < K; k0 += 64, bi ^= 1) {
        __syncthreads();
        if (k0 + 64 < K) stage(k0 + 64, bi ^ 1);
        compute(bi);
    }

    #pragma unroll
    for (int i = 0; i < 2; i++) {
        #pragma unroll
        for (int j = 0; j < 2; j++) {
            int col = n0 + wcol * 32 + j * 16 + l16;
            float bv = bias[col];
            #pragma unroll
            for (int r = 0; r < 4; r++) {
                int row = m0 + wr * 32 + i * 16 + quad * 4 + r;
                outp[(size_t)row * N + col] = acc[i][j][r] + bv + res[(size_t)row * N + col];
            }
        }
    }
}

// ---------------- Flash attention v14 (r9-validated): in-register P + pre-permuted V ----------------
// 41.4us, 0 bank conflicts. Swapped QK^T (S^T = mfma(K,Q)), cvt_pk pa pack, no Ps
// buffer (LDS 32768), scalar l_part, exp2 softmax, b128 PV via permuted vt.
__global__ __launch_bounds__(256) void k_flash(
    const bf16* __restrict__ qkv, const bf16* __restrict__ vt, bf16* __restrict__ y)
{
    __shared__ __align__(16) bf16 Ks[2][64 * 64];      // [buf][key][d ^ swz]
    __shared__ __align__(16) bf16 VTl[2][64 * 64];     // [buf][d][permuted-key ^ swz]
    int bid = blockIdx.x;
    int hi = bid >> 8;                   // 0..2
    int lo = bid & 255;
    int g  = lo >> 3;                    // 0..31
    int e  = lo & 7;                     // 0..7
    int bh = hi * 8 + e;                 // 0..23
    int qt;
    if      (hi == 0) qt = g;
    else if (hi == 1) qt = (g + 16) & 31;
    else              qt = (g < 16) ? (30 - 2 * g) : (63 - 2 * g);
    int b = bh / N_HEAD, h = bh % N_HEAD;
    int t = threadIdx.x, lane = t & 63, wave = t >> 6;
    int quad = lane >> 4, l16 = lane & 15;
    int qbase = qt * 64 + wave * 16;
    int qself = qbase + l16;             // this lane's q row (after swap)

    // Q fragments, pre-scaled by log2(e)/8 (softmax uses exp2)
    bf16x8 qa[2];
    {
        const float qsc = 0.125f * 1.44269504089f;
        const bf16* qrow = qkv + (size_t)(b * SEQ + qbase + l16) * C3 + h * 64;
        #pragma unroll
        for (int kh = 0; kh < 2; kh++) {
            union { uint4 u4; bf16 e8[8]; bf16x8 vv; } uq;
            uq.u4 = *(const uint4*)&qrow[quad * 8 + kh * 32];
            #pragma unroll
            for (int j = 0; j < 8; j++) uq.e8[j] = (bf16)((float)uq.e8[j] * qsc);
            qa[kh] = uq.vv;
        }
    }
    float l_part = 0.f;                  // scalar: sum over this lane's keys for q=l16
    f32x4 o[4];
    #pragma unroll
    for (int j = 0; j < 4; j++) o[j] = (f32x4){0.f, 0.f, 0.f, 0.f};

    int sr = t >> 3;                 // 0..31 (staging row)
    int sc = t & 7;                  // 16B chunk
    int gsw = (sc ^ (sr & 7)) * 8;   // swizzled column offset (shared by K and V)

    const bf16* kg = qkv + (size_t)b * SEQ * C3 + N_EMBD + h * 64;
    const bf16* vg = vt + (size_t)bh * 64 * SEQ;

    auto stage = [&](int tile, int bufi) {
        int k0 = tile * 64;
        #pragma unroll
        for (int p = 0; p < 2; p++) {
            int rr = sr + 32 * p;
            async16(&kg[(size_t)(k0 + rr) * C3 + gsw], &Ks[bufi][rr * 64 + sc * 8]);
            async16(&vg[(size_t)rr * SEQ + k0 + gsw], &VTl[bufi][rr * 64 + sc * 8]);
        }
    };

    int ntiles = qt + 1;
    stage(0, 0);

    for (int tt = 0; tt < ntiles; tt++) {
        int bufi = tt & 1;
        int k0 = tt * 64;
        __syncthreads();                       // drains buf's loads (issued a full tile ago)
        if (tt + 1 < ntiles) stage(tt + 1, bufi ^ 1);

        // S^T = K Q^T (swapped operands; K read identical to v10)
        // s[nt]: lane holds S[key = k0+nt*16+quad*4+r][q = qbase+l16]
        f32x4 s[4];
        __builtin_amdgcn_s_setprio(1);
        #pragma unroll
        for (int nt = 0; nt < 4; nt++) {
            bf16x8 b0 = *(bf16x8*)&Ks[bufi][(nt * 16 + l16) * 64 + (((quad    ) ^ (l16 & 7)) * 8)];
            bf16x8 b1 = *(bf16x8*)&Ks[bufi][(nt * 16 + l16) * 64 + (((quad + 4) ^ (l16 & 7)) * 8)];
            f32x4 z = (f32x4){0.f, 0.f, 0.f, 0.f};
            z = __builtin_amdgcn_mfma_f32_16x16x32_bf16(b0, qa[0], z, 0, 0, 0);
            z = __builtin_amdgcn_mfma_f32_16x16x32_bf16(b1, qa[1], z, 0, 0, 0);
            s[nt] = z;
        }
        __builtin_amdgcn_s_setprio(0);

        // p = exp2(s); causal zeroing only on the diagonal tile; l_part scalar
        bool diag = (tt == qt);
        float p[4][4];
        #pragma unroll
        for (int nt = 0; nt < 4; nt++) {
            int keyb = k0 + nt * 16 + quad * 4;
            #pragma unroll
            for (int r = 0; r < 4; r++) {
                float pv = exp2f(s[nt][r]);
                if (diag && keyb + r > qself) pv = 0.f;
                p[nt][r] = pv;
                l_part += pv;
            }
        }

        // pa: packed-placement build via v_cvt_pk_bf16_f32 (8 ops)
        // pa[kt].e8 = { P[kt*32+quad*4+0..3], P[kt*32+16+quad*4+0..3] } (permuted k-axis)
        bf16x8 pa[2];
        #pragma unroll
        for (int kt = 0; kt < 2; kt++) {
            union { unsigned u[4]; bf16x8 vv; } pk;
            pk.u[0] = cvt_pk_bf16(p[2 * kt][0],     p[2 * kt][1]);
            pk.u[1] = cvt_pk_bf16(p[2 * kt][2],     p[2 * kt][3]);
            pk.u[2] = cvt_pk_bf16(p[2 * kt + 1][0], p[2 * kt + 1][1]);
            pk.u[3] = cvt_pk_bf16(p[2 * kt + 1][2], p[2 * kt + 1][3]);
            pa[kt] = pk.vv;
        }

        // O += P V : pre-permuted vt makes the fragment one b128 (v10's conflict-free pattern)
        __builtin_amdgcn_s_setprio(1);
        #pragma unroll
        for (int jt = 0; jt < 4; jt++) {
            int d = jt * 16 + l16;
            #pragma unroll
            for (int kt = 0; kt < 2; kt++) {
                bf16x8 vb = *(bf16x8*)&VTl[bufi][d * 64 + (((quad + 4 * kt) ^ (l16 & 7)) * 8)];
                o[jt] = __builtin_amdgcn_mfma_f32_16x16x32_bf16(pa[kt], vb, o[jt], 0, 0, 0);
            }
        }
        __builtin_amdgcn_s_setprio(0);
    }

    // epilogue: finish l over all keys (reduce across quads), redistribute to o's q rows
    l_part += __shfl_xor(l_part, 16);
    l_part += __shfl_xor(l_part, 32);    // now lane (l16, any quad) holds total for q=l16
    float inv[4];
    #pragma unroll
    for (int r = 0; r < 4; r++)
        inv[r] = 1.f / __shfl(l_part, quad * 4 + r);   // lane quad*4+r holds q=quad*4+r
    #pragma unroll
    for (int jt = 0; jt < 4; jt++)
        #pragma unroll
        for (int r = 0; r < 4; r++) {
            int q = qbase + quad * 4 + r;
            y[(size_t)(b * SEQ + q) * N_EMBD + h * 64 + jt * 16 + l16] =
                (bf16)(o[jt][r] * inv[r]);
        }
}

// ---------------- launcher ----------------
extern "C" void kernel_launch(void* const* d_in, const int* in_sizes, int n_in,
                              void* d_out, int out_size, void* d_ws, size_t ws_size,
                              hipStream_t stream) {
    const float* x           = (const float*)d_in[0];
    const float* ln1_g       = (const float*)d_in[1];
    const float* ln1_b       = (const float*)d_in[2];
    const float* w_attn      = (const float*)d_in[3];
    const float* b_attn      = (const float*)d_in[4];
    const float* w_attn_proj = (const float*)d_in[5];
    const float* b_attn_proj = (const float*)d_in[6];
    const float* ln2_g       = (const float*)d_in[7];
    const float* ln2_b       = (const float*)d_in[8];
    const float* w_fc        = (const float*)d_in[9];
    const float* b_fc        = (const float*)d_in[10];
    const float* w_mlp_proj  = (const float*)d_in[11];
    const float* b_mlp_proj  = (const float*)d_in[12];

    char* ws = (char*)d_ws;
    size_t off = 0;
    auto alloc = [&](size_t n) -> void* {
        off = (off + 255) & ~(size_t)255;
        void* p = ws + off;
        off += n;
        return p;
    };
    bf16* wqkvT  = (bf16*)alloc((size_t)C3 * N_EMBD * 2);
    bf16* wprojT = (bf16*)alloc((size_t)N_EMBD * N_EMBD * 2);
    bf16* wfcT   = (bf16*)alloc((size_t)4 * N_EMBD * N_EMBD * 2);
    bf16* wmlpT  = (bf16*)alloc((size_t)N_EMBD * 4 * N_EMBD * 2);
    bf16* hbuf   = (bf16*)alloc((size_t)ROWS * N_EMBD * 2);
    float* x2    = (float*)alloc((size_t)ROWS * N_EMBD * 4);
    bf16* yb     = (bf16*)alloc((size_t)ROWS * N_EMBD * 2);
    bf16* vtb    = (bf16*)alloc((size_t)BATCH * N_HEAD * 64 * SEQ * 2);
    bf16* big    = (bf16*)alloc((size_t)ROWS * 4 * N_EMBD * 2);
    bf16* qkvb   = big;        // [ROWS, 2304]
    bf16* actb   = big;        // [ROWS, 3072]

    k_transpose_all<<<6912, 256, 0, stream>>>(w_attn, wqkvT, w_attn_proj, wprojT,
                                              w_fc, wfcT, w_mlp_proj, wmlpT);

    k_layernorm<<<ROWS / 4, 256, 0, stream>>>(x, ln1_g, ln1_b, hbuf);
    // qkv: m-fast grid, BN=128, BK=32, 3-deep counted-vmcnt pipeline (PIPE=2)
    k_gemm<128, 32, 0, false, true,  true,  2><<<dim3(ROWS / 128, C3 / 128), 256, 0, stream>>>(
        hbuf, wqkvT,  b_attn,      nullptr, qkvb, ROWS, C3,     N_EMBD);
    k_vtrans<<<dim3(SEQ / 32, BATCH * N_HEAD, 2), 256, 0, stream>>>(qkvb, vtb);
    k_flash<<<768, 256, 0, stream>>>(qkvb, vtb, yb);
    // proj: 64x64 4-wave blocks, 3 blocks/CU
    k_gemm2<<<dim3(ROWS / 64, N_EMBD / 64), 256, 0, stream>>>(
        yb,   wprojT, b_attn_proj, x,       x2,   ROWS, N_EMBD, N_EMBD);
    k_layernorm<<<ROWS / 4, 256, 0, stream>>>(x2, ln2_g, ln2_b, hbuf);
    // fc: m-fast grid, BN=128, BK=32, PIPE=2
    k_gemm<128, 32, 1, false, true,  true,  2><<<dim3(ROWS / 128, 3072 / 128), 256, 0, stream>>>(
        hbuf, wfcT,   b_fc,        nullptr, actb, ROWS, 3072,   N_EMBD);
    // mlp: 64x64 4-wave blocks, 3 blocks/CU
    k_gemm2<<<dim3(ROWS / 64, N_EMBD / 64), 256, 0, stream>>>(
        actb, wmlpT,  b_mlp_proj,  x2, (float*)d_out, ROWS, N_EMBD, 3072);
}

// Round 12
// 258.594 us; speedup vs baseline: 1.0149x; 1.0006x over previous
//
#include <hip/hip_runtime.h>
#include <hip/hip_bf16.h>
#include <math.h>

#define N_EMBD 768
#define N_HEAD 12
#define BATCH  2
#define SEQ    2048
#define ROWS   (BATCH*SEQ)   // 4096
#define C3     (3*N_EMBD)    // 2304

typedef __bf16 bf16;
typedef __attribute__((ext_vector_type(8))) __bf16 bf16x8;
typedef __attribute__((ext_vector_type(4))) float f32x4;

// async global->LDS, 16B per lane. LDS dest must be wave-uniform base + 16*lane.
__device__ __forceinline__ void async16(const bf16* g, bf16* l) {
    __builtin_amdgcn_global_load_lds(
        (const __attribute__((address_space(1))) uint32_t*)g,
        (__attribute__((address_space(3))) uint32_t*)l, 16, 0, 0);
}

// packed bf16 convert: w.lo = bf16(a), w.hi = bf16(b)
__device__ __forceinline__ unsigned cvt_pk_bf16(float a, float b) {
    unsigned w;
    asm("v_cvt_pk_bf16_f32 %0, %1, %2" : "=v"(w) : "v"(a), "v"(b));
    return w;
}

// ---------------- merged transpose+cast for all 4 weights: in[K,N] -> out[N,K] ----------------
__global__ __launch_bounds__(256) void k_transpose_all(
    const float* __restrict__ w0, bf16* __restrict__ o0,   // attn K=768  N=2304 (1728 tiles)
    const float* __restrict__ w1, bf16* __restrict__ o1,   // proj K=768  N=768  (576)
    const float* __restrict__ w2, bf16* __restrict__ o2,   // fc   K=768  N=3072 (2304)
    const float* __restrict__ w3, bf16* __restrict__ o3)   // mlp  K=3072 N=768  (2304)
{
    __shared__ bf16 tile[32][33];
    int bid = blockIdx.x;
    const float* in; bf16* out; int K, N, local;
    if      (bid < 1728) { in = w0; out = o0; K = 768;  N = 2304; local = bid; }
    else if (bid < 2304) { in = w1; out = o1; K = 768;  N = 768;  local = bid - 1728; }
    else if (bid < 4608) { in = w2; out = o2; K = 768;  N = 3072; local = bid - 2304; }
    else                 { in = w3; out = o3; K = 3072; N = 768;  local = bid - 4608; }
    int nt = N / 32;
    int n0 = (local % nt) * 32, k0 = (local / nt) * 32;
    int tc = threadIdx.x & 31, tr = threadIdx.x >> 5;
    #pragma unroll
    for (int i = 0; i < 4; i++) {
        int r = tr + i * 8;
        tile[r][tc] = (bf16)in[(size_t)(k0 + r) * N + n0 + tc];
    }
    __syncthreads();
    #pragma unroll
    for (int i = 0; i < 4; i++) {
        int r = tr + i * 8;
        out[(size_t)(n0 + r) * K + k0 + tc] = tile[tc][r];
    }
}

// ---------------- V transpose: qkv[t][2C + h*64 + d] -> vt[(bh*64+d)*SEQ + P(t)] ----------------
// Keys within each 32-group written in PERMUTED order
//   P(t) = ((t&15)>>2)*8 + ((t>>4)<<2) + (t&3)
// so chunk c of 8 holds keys {4c..4c+3, 16+4c..16+4c+3}. A PV fragment (kt,quad) is then
// ONE contiguous 16B chunk -> flash reads V as conflict-free ds_read_b128 (v10 pattern)
// while keeping in-register P.
__global__ __launch_bounds__(256) void k_vtrans(
    const bf16* __restrict__ qkv, bf16* __restrict__ vt)
{
    __shared__ bf16 tile[32][33];
    int tt = blockIdx.x;                 // t tile (SEQ/32)
    int bh = blockIdx.y;                 // 24
    int dt = blockIdx.z;                 // d tile (2)
    int b = bh / N_HEAD, h = bh % N_HEAD;
    int tc = threadIdx.x & 31, tr = threadIdx.x >> 5;
    #pragma unroll
    for (int i = 0; i < 4; i++) {
        int r = tr + i * 8;              // t offset
        tile[r][tc] = qkv[(size_t)(b * SEQ + tt * 32 + r) * C3 + 2 * N_EMBD + h * 64 + dt * 32 + tc];
    }
    __syncthreads();
    int pos = ((tc & 15) >> 2) * 8 + ((tc >> 4) << 2) + (tc & 3);   // key permutation
    #pragma unroll
    for (int i = 0; i < 4; i++) {
        int r = tr + i * 8;              // d offset
        vt[(size_t)(bh * 64 + dt * 32 + r) * SEQ + tt * 32 + pos] = tile[tc][r];
    }
}

// ---------------- LayerNorm fp32 -> bf16, one wave per row, float4 loads ----------------
__global__ __launch_bounds__(256) void k_layernorm(
    const float* __restrict__ x, const float* __restrict__ g,
    const float* __restrict__ b, bf16* __restrict__ out)
{
    int wave = threadIdx.x >> 6, lane = threadIdx.x & 63;
    int row = blockIdx.x * 4 + wave;
    const float4* xr = (const float4*)(x + (size_t)row * N_EMBD);
    const float4* g4 = (const float4*)g;
    const float4* b4 = (const float4*)b;
    float4 v[3];
    float s = 0.f, sq = 0.f;
    #pragma unroll
    for (int i = 0; i < 3; i++) {
        v[i] = xr[lane + 64 * i];
        s  += v[i].x + v[i].y + v[i].z + v[i].w;
        sq += v[i].x * v[i].x + v[i].y * v[i].y + v[i].z * v[i].z + v[i].w * v[i].w;
    }
    #pragma unroll
    for (int off = 32; off > 0; off >>= 1) {
        s  += __shfl_xor(s, off);
        sq += __shfl_xor(sq, off);
    }
    float mu  = s * (1.f / N_EMBD);
    float var = sq * (1.f / N_EMBD) - mu * mu;
    float rs  = rsqrtf(var + 1e-5f);
    bf16* orow = out + (size_t)row * N_EMBD;
    #pragma unroll
    for (int i = 0; i < 3; i++) {
        float4 gv = g4[lane + 64 * i], bv = b4[lane + 64 * i];
        union { ushort4 u4; bf16 e[4]; } pk;
        pk.e[0] = (bf16)((v[i].x - mu) * rs * gv.x + bv.x);
        pk.e[1] = (bf16)((v[i].y - mu) * rs * gv.y + bv.y);
        pk.e[2] = (bf16)((v[i].z - mu) * rs * gv.z + bv.z);
        pk.e[3] = (bf16)((v[i].w - mu) * rs * gv.w + bv.w);
        *(ushort4*)&orow[(lane + 64 * i) * 4] = pk.u4;
    }
}

// ---------------- GEMM (4-wave, 128xBN, BK templated) ----------------
// PIPE=2 (r11-validated, +qkv/fc): 3-buffer counted-vmcnt pipeline. s_waitcnt vmcnt(4)
// waits ONLY stage(k); stage(k+1) stays in flight across the raw s_barrier; stage(k+2)
// issued after. Loads get 2 full iterations to land. Safety: barrier-after-waitcnt
// publishes all waves' parts; buffer (k+2)%3 only rewritten after the barrier that
// proves compute(k-1) done; tail peels to vmcnt(0).
template<int BN, int BK, int ACT, bool RES, bool OUT_BF16, bool MSWAP, int PIPE>
__global__ __launch_bounds__(256) void k_gemm(
    const bf16* __restrict__ A, const bf16* __restrict__ Bt,
    const float* __restrict__ bias, const float* __restrict__ res,
    void* __restrict__ outp, int M, int N, int K)
{
    constexpr int WC  = BN / 64;
    constexpr int WR  = 4 / WC;
    constexpr int RPW = 128 / WR;
    constexpr int MI  = RPW / 16;
    constexpr int NB  = (PIPE == 2) ? 3 : (PIPE == 1 ? 2 : 1);
    constexpr int KH  = BK / 32;          // 16x16x32 passes per K-step
    constexpr int CPR = BK / 8;           // 16B chunks per row
    constexpr int RSTEP = 256 / CPR;      // rows staged per pass
    __shared__ __align__(16) bf16 As[NB][128 * BK];
    __shared__ __align__(16) bf16 Bs[NB][BN * BK];
    int n0 = (MSWAP ? blockIdx.y : blockIdx.x) * BN;
    int m0 = (MSWAP ? blockIdx.x : blockIdx.y) * 128;
    int t = threadIdx.x;
    int lane = t & 63, wave = t >> 6;
    int wr = wave / WC, wc = wave % WC;
    int quad = lane >> 4, l16 = lane & 15;

    f32x4 acc[MI][4];
    #pragma unroll
    for (int i = 0; i < MI; i++)
        #pragma unroll
        for (int j = 0; j < 4; j++) acc[i][j] = (f32x4){0.f, 0.f, 0.f, 0.f};

    int sr = t / CPR;           // staging row
    int sc = t % CPR;           // staging chunk
    int fsw = (BK == 64) ? (sr & 7) : ((sr & 3) ^ ((sr >> 2) & 3));
    int gsw = (sc ^ fsw) * 8;   // swizzled global column offset
    int lsw = (BK == 64) ? (l16 & 7) : ((l16 & 3) ^ ((l16 >> 2) & 3));

    auto stage = [&](int k0, int bi) {
        #pragma unroll
        for (int p = 0; p < 128 / RSTEP; p++) {
            int r = sr + p * RSTEP;
            async16(&A[(size_t)(m0 + r) * K + k0 + gsw], &As[bi][r * BK + sc * 8]);
        }
        #pragma unroll
        for (int p = 0; p < BN / RSTEP; p++) {
            int r = sr + p * RSTEP;
            async16(&Bt[(size_t)(n0 + r) * K + k0 + gsw], &Bs[bi][r * BK + sc * 8]);
        }
    };
    auto compute = [&](int bi) {
        #pragma unroll
        for (int kh = 0; kh < KH; kh++) {
            int qk = quad + 4 * kh;
            bf16x8 af[MI], bfv[4];
            #pragma unroll
            for (int i = 0; i < MI; i++)
                af[i]  = *(bf16x8*)&As[bi][(wr * RPW + i * 16 + l16) * BK + ((qk ^ lsw) * 8)];
            #pragma unroll
            for (int j = 0; j < 4; j++)
                bfv[j] = *(bf16x8*)&Bs[bi][(wc * 64 + j * 16 + l16) * BK + ((qk ^ lsw) * 8)];
            #pragma unroll
            for (int i = 0; i < MI; i++)
                #pragma unroll
                for (int j = 0; j < 4; j++)
                    acc[i][j] = __builtin_amdgcn_mfma_f32_16x16x32_bf16(af[i], bfv[j], acc[i][j], 0, 0, 0);
        }
    };

    if (PIPE == 2) {
        static_assert(PIPE != 2 || (128 + BN) / RSTEP == 4, "vmcnt(4) assumes 4 loads/stage");
        stage(0, 0);
        stage(BK, 1);
        int bi = 0;
        for (int k0 = 0; k0 < K; k0 += BK) {
            if (k0 + BK < K) asm volatile("s_waitcnt vmcnt(4)" ::: "memory");
            else             asm volatile("s_waitcnt vmcnt(0)" ::: "memory");
            __builtin_amdgcn_s_barrier();
            __builtin_amdgcn_sched_barrier(0);
            if (k0 + 2 * BK < K) {
                int b2 = bi + 2; if (b2 >= 3) b2 -= 3;
                stage(k0 + 2 * BK, b2);
            }
            compute(bi);
            bi = (bi == 2) ? 0 : bi + 1;
        }
    } else if (PIPE == 1) {
        stage(0, 0);
        int bi = 0;
        for (int k0 = 0; k0 < K; k0 += BK, bi ^= 1) {
            __syncthreads();
            if (k0 + BK < K) stage(k0 + BK, bi ^ 1);
            compute(bi);
        }
    } else {
        for (int k0 = 0; k0 < K; k0 += BK) {
            __syncthreads();
            stage(k0, 0);
            __syncthreads();
            compute(0);
        }
    }

    float* outf = (float*)outp;
    bf16*  outb = (bf16*)outp;
    #pragma unroll
    for (int i = 0; i < MI; i++) {
        #pragma unroll
        for (int j = 0; j < 4; j++) {
            int col = n0 + wc * 64 + j * 16 + l16;
            float bv = bias[col];
            #pragma unroll
            for (int r = 0; r < 4; r++) {
                int row = m0 + wr * RPW + i * 16 + quad * 4 + r;
                float v = acc[i][j][r] + bv;
                if (ACT == 1) {
                    float z = 0.7978845608f * (v + 0.044715f * v * v * v);
                    v = v / (1.f + __expf(-2.f * z));   // 0.5v(1+tanh z) == v*sigmoid(2z)
                }
                if (RES) v += res[(size_t)row * N + col];
                if (OUT_BF16) outb[(size_t)row * N + col] = (bf16)v;
                else          outf[(size_t)row * N + col] = v;
            }
        }
    }
}

// ---------------- GEMM2 (4-wave, 64x64 tile): r12 = counted-vmcnt 3-buffer pipeline ----------------
// Same T4-lite transform as k_gemm PIPE=2: 4 loads/thread/stage -> vmcnt(4), raw
// barrier, stage(k+2) after. LDS 48KB -> 3 blocks/CU = exactly the grid supply.
// mlp (K=3072, 48 K-steps) is the main beneficiary.
__global__ __launch_bounds__(256) void k_gemm2(
    const bf16* __restrict__ A, const bf16* __restrict__ Bt,
    const float* __restrict__ bias, const float* __restrict__ res,
    float* __restrict__ outp, int M, int N, int K)
{
    __shared__ __align__(16) bf16 As[3][64 * 64];
    __shared__ __align__(16) bf16 Bs[3][64 * 64];
    int m0 = blockIdx.x * 64, n0 = blockIdx.y * 64;
    int t = threadIdx.x;
    int lane = t & 63, w = t >> 6;       // w 0..3
    int wr = w >> 1, wcol = w & 1;       // 2x2 wave grid
    int quad = lane >> 4, l16 = lane & 15;

    f32x4 acc[2][2];
    #pragma unroll
    for (int i = 0; i < 2; i++)
        #pragma unroll
        for (int j = 0; j < 2; j++) acc[i][j] = (f32x4){0.f, 0.f, 0.f, 0.f};

    int sr = t >> 3;            // 0..31 (row)
    int sc = t & 7;             // chunk 0..7
    int gsw = (sc ^ (sr & 7)) * 8;   // (sr+32)&7 == sr&7

    auto stage = [&](int k0, int bi) {
        #pragma unroll
        for (int p = 0; p < 2; p++) {
            int r = sr + p * 32;
            async16(&A[(size_t)(m0 + r) * K + k0 + gsw], &As[bi][r * 64 + sc * 8]);
            async16(&Bt[(size_t)(n0 + r) * K + k0 + gsw], &Bs[bi][r * 64 + sc * 8]);
        }
    };
    auto compute = [&](int bi) {
        #pragma unroll
        for (int kh = 0; kh < 2; kh++) {
            int rsw = ((quad + 4 * kh) ^ (l16 & 7)) * 8;
            bf16x8 af[2], bfv[2];
            #pragma unroll
            for (int i = 0; i < 2; i++)
                af[i]  = *(bf16x8*)&As[bi][(wr * 32 + i * 16 + l16) * 64 + rsw];
            #pragma unroll
            for (int j = 0; j < 2; j++)
                bfv[j] = *(bf16x8*)&Bs[bi][(wcol * 32 + j * 16 + l16) * 64 + rsw];
            #pragma unroll
            for (int i = 0; i < 2; i++)
                #pragma unroll
                for (int j = 0; j < 2; j++)
                    acc[i][j] = __builtin_amdgcn_mfma_f32_16x16x32_bf16(af[i], bfv[j], acc[i][j], 0, 0, 0);
        }
    };

    stage(0, 0);
    stage(64, 1);
    int bi = 0;
    for (int k0 = 0; k0 < K; k0 += 64) {
        if (k0 + 64 < K) asm volatile("s_waitcnt vmcnt(4)" ::: "memory");
        else             asm volatile("s_waitcnt vmcnt(0)" ::: "memory");
        __builtin_amdgcn_s_barrier();
        __builtin_amdgcn_sched_barrier(0);
        if (k0 + 128 < K) {
            int b2 = bi + 2; if (b2 >= 3) b2 -= 3;
            stage(k0 + 128, b2);
        }
        compute(bi);
        bi = (bi == 2) ? 0 : bi + 1;
    }

    #pragma unroll
    for (int i = 0; i < 2; i++) {
        #pragma unroll
        for (int j = 0; j < 2; j++) {
            int col = n0 + wcol * 32 + j * 16 + l16;
            float bv = bias[col];
            #pragma unroll
            for (int r = 0; r < 4; r++) {
                int row = m0 + wr * 32 + i * 16 + quad * 4 + r;
                outp[(size_t)row * N + col] = acc[i][j][r] + bv + res[(size_t)row * N + col];
            }
        }
    }
}

// ---------------- Flash attention v15: v14 + counted-vmcnt 3-buffer pipeline ----------------
// v14 core (in-register P, pre-permuted V b128 PV, cvt_pk pack, exp2) + the r11/r12
// T4-lite staging: 3 buffers, s_waitcnt vmcnt(4) (stage(t+1) stays in flight across
// the raw barrier), stage(t+2) after. LDS 49152 -> 3 blocks/CU = grid supply.
__global__ __launch_bounds__(256) void k_flash(
    const bf16* __restrict__ qkv, const bf16* __restrict__ vt, bf16* __restrict__ y)
{
    __shared__ __align__(16) bf16 Ks[3][64 * 64];      // [buf][key][d ^ swz]
    __shared__ __align__(16) bf16 VTl[3][64 * 64];     // [buf][d][permuted-key ^ swz]
    int bid = blockIdx.x;
    int hi = bid >> 8;                   // 0..2
    int lo = bid & 255;
    int g  = lo >> 3;                    // 0..31
    int e  = lo & 7;                     // 0..7
    int bh = hi * 8 + e;                 // 0..23
    int qt;
    if      (hi == 0) qt = g;
    else if (hi == 1) qt = (g + 16) & 31;
    else              qt = (g < 16) ? (30 - 2 * g) : (63 - 2 * g);
    int b = bh / N_HEAD, h = bh % N_HEAD;
    int t = threadIdx.x, lane = t & 63, wave = t >> 6;
    int quad = lane >> 4, l16 = lane & 15;
    int qbase = qt * 64 + wave * 16;
    int qself = qbase + l16;             // this lane's q row (after swap)

    // Q fragments, pre-scaled by log2(e)/8 (softmax uses exp2)
    bf16x8 qa[2];
    {
        const float qsc = 0.125f * 1.44269504089f;
        const bf16* qrow = qkv + (size_t)(b * SEQ + qbase + l16) * C3 + h * 64;
        #pragma unroll
        for (int kh = 0; kh < 2; kh++) {
            union { uint4 u4; bf16 e8[8]; bf16x8 vv; } uq;
            uq.u4 = *(const uint4*)&qrow[quad * 8 + kh * 32];
            #pragma unroll
            for (int j = 0; j < 8; j++) uq.e8[j] = (bf16)((float)uq.e8[j] * qsc);
            qa[kh] = uq.vv;
        }
    }
    float l_part = 0.f;                  // scalar: sum over this lane's keys for q=l16
    f32x4 o[4];
    #pragma unroll
    for (int j = 0; j < 4; j++) o[j] = (f32x4){0.f, 0.f, 0.f, 0.f};

    int sr = t >> 3;                 // 0..31 (staging row)
    int sc = t & 7;                  // 16B chunk
    int gsw = (sc ^ (sr & 7)) * 8;   // swizzled column offset (shared by K and V)

    const bf16* kg = qkv + (size_t)b * SEQ * C3 + N_EMBD + h * 64;
    const bf16* vg = vt + (size_t)bh * 64 * SEQ;

    auto stage = [&](int tile, int bufi) {
        int k0 = tile * 64;
        #pragma unroll
        for (int p = 0; p < 2; p++) {
            int rr = sr + 32 * p;
            async16(&kg[(size_t)(k0 + rr) * C3 + gsw], &Ks[bufi][rr * 64 + sc * 8]);
            async16(&vg[(size_t)rr * SEQ + k0 + gsw], &VTl[bufi][rr * 64 + sc * 8]);
        }
    };

    int ntiles = qt + 1;
    stage(0, 0);
    if (ntiles > 1) stage(1, 1);

    int bi = 0;
    for (int tt = 0; tt < ntiles; tt++) {
        int k0 = tt * 64;
        if (tt + 1 < ntiles) asm volatile("s_waitcnt vmcnt(4)" ::: "memory");
        else                 asm volatile("s_waitcnt vmcnt(0)" ::: "memory");
        __builtin_amdgcn_s_barrier();
        __builtin_amdgcn_sched_barrier(0);
        if (tt + 2 < ntiles) {
            int b2 = bi + 2; if (b2 >= 3) b2 -= 3;
            stage(tt + 2, b2);
        }

        // S^T = K Q^T (swapped operands)
        // s[nt]: lane holds S[key = k0+nt*16+quad*4+r][q = qbase+l16]
        f32x4 s[4];
        __builtin_amdgcn_s_setprio(1);
        #pragma unroll
        for (int nt = 0; nt < 4; nt++) {
            bf16x8 b0 = *(bf16x8*)&Ks[bi][(nt * 16 + l16) * 64 + (((quad    ) ^ (l16 & 7)) * 8)];
            bf16x8 b1 = *(bf16x8*)&Ks[bi][(nt * 16 + l16) * 64 + (((quad + 4) ^ (l16 & 7)) * 8)];
            f32x4 z = (f32x4){0.f, 0.f, 0.f, 0.f};
            z = __builtin_amdgcn_mfma_f32_16x16x32_bf16(b0, qa[0], z, 0, 0, 0);
            z = __builtin_amdgcn_mfma_f32_16x16x32_bf16(b1, qa[1], z, 0, 0, 0);
            s[nt] = z;
        }
        __builtin_amdgcn_s_setprio(0);

        // p = exp2(s); causal zeroing only on the diagonal tile; l_part scalar
        bool diag = (tt == qt);
        float p[4][4];
        #pragma unroll
        for (int nt = 0; nt < 4; nt++) {
            int keyb = k0 + nt * 16 + quad * 4;
            #pragma unroll
            for (int r = 0; r < 4; r++) {
                float pv = exp2f(s[nt][r]);
                if (diag && keyb + r > qself) pv = 0.f;
                p[nt][r] = pv;
                l_part += pv;
            }
        }

        // pa: packed-placement build via v_cvt_pk_bf16_f32 (8 ops)
        // pa[kt].e8 = { P[kt*32+quad*4+0..3], P[kt*32+16+quad*4+0..3] } (permuted k-axis)
        bf16x8 pa[2];
        #pragma unroll
        for (int kt = 0; kt < 2; kt++) {
            union { unsigned u[4]; bf16x8 vv; } pk;
            pk.u[0] = cvt_pk_bf16(p[2 * kt][0],     p[2 * kt][1]);
            pk.u[1] = cvt_pk_bf16(p[2 * kt][2],     p[2 * kt][3]);
            pk.u[2] = cvt_pk_bf16(p[2 * kt + 1][0], p[2 * kt + 1][1]);
            pk.u[3] = cvt_pk_bf16(p[2 * kt + 1][2], p[2 * kt + 1][3]);
            pa[kt] = pk.vv;
        }

        // O += P V : pre-permuted vt makes the fragment one b128 (conflict-free)
        __builtin_amdgcn_s_setprio(1);
        #pragma unroll
        for (int jt = 0; jt < 4; jt++) {
            int d = jt * 16 + l16;
            #pragma unroll
            for (int kt = 0; kt < 2; kt++) {
                bf16x8 vb = *(bf16x8*)&VTl[bi][d * 64 + (((quad + 4 * kt) ^ (l16 & 7)) * 8)];
                o[jt] = __builtin_amdgcn_mfma_f32_16x16x32_bf16(pa[kt], vb, o[jt], 0, 0, 0);
            }
        }
        __builtin_amdgcn_s_setprio(0);
        bi = (bi == 2) ? 0 : bi + 1;
    }

    // epilogue: finish l over all keys (reduce across quads), redistribute to o's q rows
    l_part += __shfl_xor(l_part, 16);
    l_part += __shfl_xor(l_part, 32);    // now lane (l16, any quad) holds total for q=l16
    float inv[4];
    #pragma unroll
    for (int r = 0; r < 4; r++)
        inv[r] = 1.f / __shfl(l_part, quad * 4 + r);   // lane quad*4+r holds q=quad*4+r
    #pragma unroll
    for (int jt = 0; jt < 4; jt++)
        #pragma unroll
        for (int r = 0; r < 4; r++) {
            int q = qbase + quad * 4 + r;
            y[(size_t)(b * SEQ + q) * N_EMBD + h * 64 + jt * 16 + l16] =
                (bf16)(o[jt][r] * inv[r]);
        }
}

// ---------------- launcher ----------------
extern "C" void kernel_launch(void* const* d_in, const int* in_sizes, int n_in,
                              void* d_out, int out_size, void* d_ws, size_t ws_size,
                              hipStream_t stream) {
    const float* x           = (const float*)d_in[0];
    const float* ln1_g       = (const float*)d_in[1];
    const float* ln1_b       = (const float*)d_in[2];
    const float* w_attn      = (const float*)d_in[3];
    const float* b_attn      = (const float*)d_in[4];
    const float* w_attn_proj = (const float*)d_in[5];
    const float* b_attn_proj = (const float*)d_in[6];
    const float* ln2_g       = (const float*)d_in[7];
    const float* ln2_b       = (const float*)d_in[8];
    const float* w_fc        = (const float*)d_in[9];
    const float* b_fc        = (const float*)d_in[10];
    const float* w_mlp_proj  = (const float*)d_in[11];
    const float* b_mlp_proj  = (const float*)d_in[12];

    char* ws = (char*)d_ws;
    size_t off = 0;
    auto alloc = [&](size_t n) -> void* {
        off = (off + 255) & ~(size_t)255;
        void* p = ws + off;
        off += n;
        return p;
    };
    bf16* wqkvT  = (bf16*)alloc((size_t)C3 * N_EMBD * 2);
    bf16* wprojT = (bf16*)alloc((size_t)N_EMBD * N_EMBD * 2);
    bf16* wfcT   = (bf16*)alloc((size_t)4 * N_EMBD * N_EMBD * 2);
    bf16* wmlpT  = (bf16*)alloc((size_t)N_EMBD * 4 * N_EMBD * 2);
    bf16* hbuf   = (bf16*)alloc((size_t)ROWS * N_EMBD * 2);
    float* x2    = (float*)alloc((size_t)ROWS * N_EMBD * 4);
    bf16* yb     = (bf16*)alloc((size_t)ROWS * N_EMBD * 2);
    bf16* vtb    = (bf16*)alloc((size_t)BATCH * N_HEAD * 64 * SEQ * 2);
    bf16* big    = (bf16*)alloc((size_t)ROWS * 4 * N_EMBD * 2);
    bf16* qkvb   = big;        // [ROWS, 2304]
    bf16* actb   = big;        // [ROWS, 3072]

    k_transpose_all<<<6912, 256, 0, stream>>>(w_attn, wqkvT, w_attn_proj, wprojT,
                                              w_fc, wfcT, w_mlp_proj, wmlpT);

    k_layernorm<<<ROWS / 4, 256, 0, stream>>>(x, ln1_g, ln1_b, hbuf);
    // qkv: m-fast grid, BN=128, BK=32, 3-deep counted-vmcnt pipeline (PIPE=2)
    k_gemm<128, 32, 0, false, true,  true,  2><<<dim3(ROWS / 128, C3 / 128), 256, 0, stream>>>(
        hbuf, wqkvT,  b_attn,      nullptr, qkvb, ROWS, C3,     N_EMBD);
    k_vtrans<<<dim3(SEQ / 32, BATCH * N_HEAD, 2), 256, 0, stream>>>(qkvb, vtb);
    k_flash<<<768, 256, 0, stream>>>(qkvb, vtb, yb);
    // proj: 64x64 4-wave blocks, counted-vmcnt pipeline
    k_gemm2<<<dim3(ROWS / 64, N_EMBD / 64), 256, 0, stream>>>(
        yb,   wprojT, b_attn_proj, x,       x2,   ROWS, N_EMBD, N_EMBD);
    k_layernorm<<<ROWS / 4, 256, 0, stream>>>(x2, ln2_g, ln2_b, hbuf);
    // fc: m-fast grid, BN=128, BK=32, PIPE=2
    k_gemm<128, 32, 1, false, true,  true,  2><<<dim3(ROWS / 128, 3072 / 128), 256, 0, stream>>>(
        hbuf, wfcT,   b_fc,        nullptr, actb, ROWS, 3072,   N_EMBD);
    // mlp: 64x64 4-wave blocks, counted-vmcnt pipeline
    k_gemm2<<<dim3(ROWS / 64, N_EMBD / 64), 256, 0, stream>>>(
        actb, wmlpT,  b_mlp_proj,  x2, (float*)d_out, ROWS, N_EMBD, 3072);
}